// Round 9
// baseline (1110.951 us; speedup 1.0000x reference)
//
#include <hip/hip_runtime.h>
#include <hip/hip_fp16.h>
#include <cstdint>
#include <cstddef>

#define BS 8
#define TT 256
#define DD 2048
#define NN 8192
#define KK 64
#define GG 512
#define GSZ 16
#define HH 64
#define MIN_ 69
#define MOUT_ 66
#define NSL 32     // slices per batch
#define SLN 256    // neurons per slice

typedef float    f32x4 __attribute__((ext_vector_type(4)));
typedef uint32_t u32x4 __attribute__((ext_vector_type(4)));

// ---------------- Phase A: modulator (runs once) ----------------
// One WG per group g; w1/w2/b2 staged in LDS ONCE, all 8 batches looped
// inside (R8 version — measured ~36us including launch/memset overhead).
__global__ __launch_bounds__(256) void modulator_kernel(
    const float* __restrict__ w1, const float* __restrict__ b1,
    const float* __restrict__ w2, const float* __restrict__ b2,
    const float* __restrict__ act0, const float* __restrict__ heb0,
    const float* __restrict__ dec0, const float* __restrict__ thr0,
    const float* __restrict__ nid,
    float* __restrict__ wconn, float* __restrict__ decayB, float* __restrict__ thrB)
{
  const int g = blockIdx.x, tid = threadIdx.x;
  __shared__ float w1s[MIN_ * HH];    // 4416 floats
  __shared__ float w2s[HH * MOUT_];   // 4224 floats
  __shared__ float b2s[MOUT_];
  __shared__ float xs[GSZ][MIN_];
  __shared__ float hd[GSZ * HH];

  for (int j = tid; j < MIN_ * HH; j += 256) w1s[j] = w1[(size_t)g * MIN_ * HH + j];
  for (int j = tid; j < HH * MOUT_; j += 256) w2s[j] = w2[(size_t)g * HH * MOUT_ + j];
  if (tid < MOUT_) b2s[tid] = b2[g * MOUT_ + tid];
  const float b1v = b1[g * HH + (tid & 63)];   // h = tid&63 is fixed per thread
  const int nbase = g * GSZ;

  for (int b = 0; b < BS; ++b) {
    __syncthreads();   // xs/hd free from previous batch
    for (int j = tid; j < GSZ * KK; j += 256) {
      int s = j >> 6, k = j & 63;
      xs[s][1 + k] = heb0[((size_t)(b * NN + nbase + s)) * KK + k];
    }
    if (tid < GSZ) {
      int n = nbase + tid;
      xs[tid][0]  = act0[b * NN + n];
      xs[tid][65] = dec0[b * NN + n];
      xs[tid][66] = thr0[b * NN + n];
      xs[tid][67] = nid[2 * n];
      xs[tid][68] = nid[2 * n + 1];
    }
    __syncthreads();

    #pragma unroll
    for (int rep = 0; rep < 4; ++rep) {
      int s = rep * 4 + (tid >> 6), h = tid & 63;
      float acc = b1v;
      for (int i = 0; i < MIN_; ++i) acc = fmaf(xs[s][i], w1s[i * HH + h], acc);
      hd[s * HH + h] = tanhf(acc);
    }
    __syncthreads();

    for (int j = tid; j < GSZ * MOUT_; j += 256) {
      int s = j / MOUT_, o = j - s * MOUT_;
      float acc = b2s[o];
      for (int h = 0; h < HH; ++h) acc = fmaf(hd[s * HH + h], w2s[h * MOUT_ + o], acc);
      int gidx = b * NN + nbase + s;
      if (o < KK)       wconn[(size_t)gidx * KK + o] = acc;
      else if (o == KK) decayB[gidx] = 1.f / (1.f + expf(-acc));
      else              thrB[gidx]   = acc;
    }
  }
}

// ---------------- Phase B: 256-step recurrent scan ----------------
// 256 WGs (batch = blockIdx&7, slice = blockIdx>>3), 256 threads, 1 neuron/thread.
// Exchange word: [tag=t+1 (hi16) | fp16 act (lo16)] — data IS the flag.
// R9 = R7 reload-as-poll (detection == data arrival, fully overlapped with
// publish latency) + SELECTIVE RE-ISSUE: retries reload only vectors whose
// tags were stale (per-lane pend bitmask, exec-predicated loads), cutting
// retry traffic ~4-8x; s_sleep(1) backoff between retries.
// All exchange ops: proven sc0 sc1 bits. WAR safety/liveness: exact-match
// tag induction identical to R6/R7 (writer publishes t+3 into pw only after
// verified t+2 reload of pw^1; peer stores t+2 only after verified t+1
// reload of pw).
__global__ __launch_bounds__(256, 1) void scan_kernel(
    const float* __restrict__ cc, const int* __restrict__ conn,
    const float* __restrict__ V0, const float* __restrict__ act0,
    const float* __restrict__ wconn, const float* __restrict__ decayB,
    const float* __restrict__ thrB,
    float* __restrict__ out, uint32_t* actbuf)
{
  const int tid = threadIdx.x;
  const int b   = blockIdx.x & 7;   // batch (XCD-grouped under round-robin)
  const int sl  = blockIdx.x >> 3;  // slice 0..31
  const int n    = sl * SLN + tid;
  const int gidx = b * NN + n;

  __shared__ float alds[NN];        // 32 KB: full act of batch b (fp32)

  // persistent per-thread state: 64 weights + 64 pre-scaled byte offsets
  f32x4 w4[16];
  int   ad[KK];
  {
    const f32x4* wr = reinterpret_cast<const f32x4*>(wconn + (size_t)gidx * KK);
    #pragma unroll
    for (int j = 0; j < 16; ++j) w4[j] = wr[j];
    const int4* ir = reinterpret_cast<const int4*>(conn + (size_t)n * KK);
    #pragma unroll
    for (int j = 0; j < KK / 4; ++j) {
      int4 v = ir[j];
      ad[4*j+0] = v.x << 2; ad[4*j+1] = v.y << 2;
      ad[4*j+2] = v.z << 2; ad[4*j+3] = v.w << 2;
    }
  }
  float V     = V0[gidx];
  float dec   = decayB[gidx];
  float onemd = 1.f - dec;
  float thr   = thrB[gidx];

  // initial act into LDS (exact fp32)
  {
    const float4* src = reinterpret_cast<const float4*>(act0 + (size_t)b * NN);
    float4* dst = reinterpret_cast<float4*>(alds);
    #pragma unroll
    for (int j = 0; j < 8; ++j) dst[tid + j * 256] = src[tid + j * 256];
  }
  __syncthreads();

  float inj = cc[((size_t)b * TT) * DD + (n >> 2)];
  const char* abase = reinterpret_cast<const char*>(alds);

  for (int t = 0; t < TT; ++t) {
    // gather + dot over 64 random neighbors (LDS reads: act only)
    float s0 = 0.f, s1 = 0.f, s2 = 0.f, s3 = 0.f;
    #pragma unroll
    for (int j = 0; j < 16; ++j) {
      s0 = fmaf(*reinterpret_cast<const float*>(abase + ad[4*j+0]), w4[j].x, s0);
      s1 = fmaf(*reinterpret_cast<const float*>(abase + ad[4*j+1]), w4[j].y, s1);
      s2 = fmaf(*reinterpret_cast<const float*>(abase + ad[4*j+2]), w4[j].z, s2);
      s3 = fmaf(*reinterpret_cast<const float*>(abase + ad[4*j+3]), w4[j].w, s3);
    }
    float recv = (s0 + s1) + (s2 + s3) + inj;
    V = dec * V + onemd * recv;
    float x = V - thr;
    float a = 1.f / (1.f + expf(-x));

    const int pw = t & 1;
    const uint32_t* src = actbuf + (size_t)pw * (BS * NN) + (size_t)b * NN;
    u32x4 vals[8];

    if (t != TT - 1) {
      // publish [tag | fp16(a)] — one dword, device-coherent
      uint32_t word = ((uint32_t)(t + 1) << 16) |
                      (uint32_t)__half_as_ushort(__float2half_rn(a));
      uint32_t* dst = actbuf + (size_t)pw * (BS * NN) + gidx;
      asm volatile("global_store_dword %0, %1, off sc0 sc1"
                   :: "v"(dst), "v"(word) : "memory");
      // attempt #1 of the reload goes out immediately — its latency hides
      // under the out-store + inj prefetch below
      #pragma unroll
      for (int j = 0; j < 8; ++j) {
        const uint32_t* p4 = src + (tid << 2) + (j << 10);
        asm volatile("global_load_dwordx4 %0, %1, off sc0 sc1"
                     : "=v"(vals[j]) : "v"(p4));
      }
    }

    // group-of-4 mean (fp32 path for output)
    float p = a + __shfl_xor(a, 1);
    p = p + __shfl_xor(p, 2);
    if ((tid & 3) == 0)
      out[((size_t)b * TT + t) * DD + sl * 64 + (tid >> 2)] = 0.25f * p;

    if (t == TT - 1) break;

    // hidden under the reload: next step's injection prefetch
    inj = cc[((size_t)b * TT + t + 1) * DD + (n >> 2)];

    // check attempt #1; selectively re-issue only stale vectors
    {
      const uint32_t expect = (uint32_t)(t + 1) << 16;
      asm volatile("s_waitcnt vmcnt(0)" ::: "memory");
      uint32_t pend = 0;
      #pragma unroll
      for (int j = 0; j < 8; ++j) {
        uint32_t bad = ((vals[j].x & 0xFFFF0000u) ^ expect) |
                       ((vals[j].y & 0xFFFF0000u) ^ expect) |
                       ((vals[j].z & 0xFFFF0000u) ^ expect) |
                       ((vals[j].w & 0xFFFF0000u) ^ expect);
        pend |= (bad ? 1u : 0u) << j;
      }
      while (__any(pend != 0)) {
        asm volatile("s_sleep 1");
        #pragma unroll
        for (int j = 0; j < 8; ++j) {
          if ((pend >> j) & 1) {
            const uint32_t* p4 = src + (tid << 2) + (j << 10);
            asm volatile("global_load_dwordx4 %0, %1, off sc0 sc1"
                         : "=v"(vals[j]) : "v"(p4));
          }
        }
        asm volatile("s_waitcnt vmcnt(0)" ::: "memory");
        #pragma unroll
        for (int j = 0; j < 8; ++j) {
          if ((pend >> j) & 1) {
            uint32_t bad = ((vals[j].x & 0xFFFF0000u) ^ expect) |
                           ((vals[j].y & 0xFFFF0000u) ^ expect) |
                           ((vals[j].z & 0xFFFF0000u) ^ expect) |
                           ((vals[j].w & 0xFFFF0000u) ^ expect);
            if (!bad) pend &= ~(1u << j);
          }
        }
      }
    }

    // unpack fp16 payloads into LDS as fp32
    {
      const int base = (tid << 2);
      #pragma unroll
      for (int j = 0; j < 8; ++j) {
        int o = base + (j << 10);
        alds[o + 0] = __half2float(__ushort_as_half((unsigned short)(vals[j].x & 0xFFFFu)));
        alds[o + 1] = __half2float(__ushort_as_half((unsigned short)(vals[j].y & 0xFFFFu)));
        alds[o + 2] = __half2float(__ushort_as_half((unsigned short)(vals[j].z & 0xFFFFu)));
        alds[o + 3] = __half2float(__ushort_as_half((unsigned short)(vals[j].w & 0xFFFFu)));
      }
    }
    __syncthreads();
  }
}

extern "C" void kernel_launch(void* const* d_in, const int* in_sizes, int n_in,
                              void* d_out, int out_size, void* d_ws, size_t ws_size,
                              hipStream_t stream)
{
  const float* cc   = (const float*)d_in[0];
  const float* w1   = (const float*)d_in[1];
  const float* b1   = (const float*)d_in[2];
  const float* w2   = (const float*)d_in[3];
  const float* b2   = (const float*)d_in[4];
  const int*   conn = (const int*)d_in[5];
  const float* nid  = (const float*)d_in[6];
  const float* V0   = (const float*)d_in[7];
  const float* act0 = (const float*)d_in[8];
  const float* heb0 = (const float*)d_in[9];
  const float* dec0 = (const float*)d_in[10];
  const float* thr0 = (const float*)d_in[11];
  float* out = (float*)d_out;

  char* ws = (char*)d_ws;
  float*    wconn  = (float*)ws;                               // 16 MB
  float*    decayB = (float*)(ws + (size_t)BS * NN * KK * 4);  // 8*8192
  float*    thrB   = decayB + BS * NN;                         // 8*8192
  uint32_t* actbuf = (uint32_t*)(thrB + BS * NN);              // 2*8*8192 dwords

  // zero tags every launch (replay-deterministic; first poll expects tag 1)
  hipMemsetAsync(actbuf, 0, 2 * BS * NN * sizeof(uint32_t), stream);

  modulator_kernel<<<dim3(GG), 256, 0, stream>>>(w1, b1, w2, b2, act0, heb0, dec0,
                                                 thr0, nid, wconn, decayB, thrB);
  scan_kernel<<<dim3(BS * NSL), 256, 0, stream>>>(cc, conn, V0, act0, wconn,
                                                  decayB, thrB, out, actbuf);
}

// Round 10
// 936.041 us; speedup vs baseline: 1.1869x; 1.1869x over previous
//
#include <hip/hip_runtime.h>
#include <hip/hip_fp16.h>
#include <cstdint>
#include <cstddef>

#define BS 8
#define TT 256
#define DD 2048
#define NN 8192
#define KK 64
#define GG 512
#define GSZ 16
#define HH 64
#define MIN_ 69
#define MOUT_ 66
#define NSL 32     // slices per batch
#define SLN 256    // neurons per slice

typedef float    f32x4 __attribute__((ext_vector_type(4)));
typedef uint32_t u32x4 __attribute__((ext_vector_type(4)));

// ---------------- Phase 0: connectivity bank-scheduling (runs once) ----------
// For each neuron n (one wave of 64 lanes per neuron, lane = orig position k):
// stable-sort the 64 neighbor indices by LDS bank (key = bank*64+lane, unique),
// then rotate by r = n&63 so that in gather round j, lane l=n&63 reads its
// ((l+j)&63)-th bank-sorted address -> lanes sweep banks in staggered phase
// (~2 lanes/bank = free, m136). Writes:
//   ad_stored[n][j] = neighbor byte-offset for round j
//   inv2[n][k]      = j position of orig neighbor k (for weight permutation)
__global__ __launch_bounds__(256) void prep_kernel(
    const int* __restrict__ conn, int* __restrict__ ad_stored,
    unsigned char* __restrict__ inv2)
{
  const int gtid = blockIdx.x * 256 + threadIdx.x;
  const int n    = gtid >> 6;
  const int lane = gtid & 63;
  int idx  = conn[(size_t)n * KK + lane];
  int bank = idx & 31;
  unsigned key = ((unsigned)bank << 6) | (unsigned)lane;
  int rank = 0;
  #pragma unroll
  for (int i = 0; i < 64; ++i) {
    unsigned ki = (unsigned)__shfl((int)key, i);
    rank += (ki < key) ? 1 : 0;
  }
  int j = (rank - (n & 63)) & 63;
  ad_stored[(size_t)n * KK + j] = idx << 2;       // pre-scaled byte offset
  inv2[(size_t)n * KK + lane]   = (unsigned char)j;
}

// ---------------- Phase A: modulator (runs once) ----------------
// R8 structure (one WG per group, weights staged once, batches looped).
// The o<KK outputs are written PRE-PERMUTED via inv2 so the scan's straight
// vector load of wconn pairs element j with ad_stored[n][j].
__global__ __launch_bounds__(256) void modulator_kernel(
    const float* __restrict__ w1, const float* __restrict__ b1,
    const float* __restrict__ w2, const float* __restrict__ b2,
    const float* __restrict__ act0, const float* __restrict__ heb0,
    const float* __restrict__ dec0, const float* __restrict__ thr0,
    const float* __restrict__ nid, const unsigned char* __restrict__ inv2,
    float* __restrict__ wconn, float* __restrict__ decayB, float* __restrict__ thrB)
{
  const int g = blockIdx.x, tid = threadIdx.x;
  __shared__ float w1s[MIN_ * HH];
  __shared__ float w2s[HH * MOUT_];
  __shared__ float b2s[MOUT_];
  __shared__ float xs[GSZ][MIN_];
  __shared__ float hd[GSZ * HH];

  for (int j = tid; j < MIN_ * HH; j += 256) w1s[j] = w1[(size_t)g * MIN_ * HH + j];
  for (int j = tid; j < HH * MOUT_; j += 256) w2s[j] = w2[(size_t)g * HH * MOUT_ + j];
  if (tid < MOUT_) b2s[tid] = b2[g * MOUT_ + tid];
  const float b1v = b1[g * HH + (tid & 63)];
  const int nbase = g * GSZ;

  for (int b = 0; b < BS; ++b) {
    __syncthreads();
    for (int j = tid; j < GSZ * KK; j += 256) {
      int s = j >> 6, k = j & 63;
      xs[s][1 + k] = heb0[((size_t)(b * NN + nbase + s)) * KK + k];
    }
    if (tid < GSZ) {
      int n = nbase + tid;
      xs[tid][0]  = act0[b * NN + n];
      xs[tid][65] = dec0[b * NN + n];
      xs[tid][66] = thr0[b * NN + n];
      xs[tid][67] = nid[2 * n];
      xs[tid][68] = nid[2 * n + 1];
    }
    __syncthreads();

    #pragma unroll
    for (int rep = 0; rep < 4; ++rep) {
      int s = rep * 4 + (tid >> 6), h = tid & 63;
      float acc = b1v;
      for (int i = 0; i < MIN_; ++i) acc = fmaf(xs[s][i], w1s[i * HH + h], acc);
      hd[s * HH + h] = tanhf(acc);
    }
    __syncthreads();

    for (int j = tid; j < GSZ * MOUT_; j += 256) {
      int s = j / MOUT_, o = j - s * MOUT_;
      float acc = b2s[o];
      for (int h = 0; h < HH; ++h) acc = fmaf(hd[s * HH + h], w2s[h * MOUT_ + o], acc);
      int nn = nbase + s;
      int gidx = b * NN + nn;
      if (o < KK) {
        int jp = inv2[(size_t)nn * KK + o];
        wconn[(size_t)gidx * KK + jp] = acc;
      }
      else if (o == KK) decayB[gidx] = 1.f / (1.f + expf(-acc));
      else              thrB[gidx]   = acc;
    }
  }
}

// ---------------- Phase B: 256-step recurrent scan (R7 protocol) ----------
// 256 WGs (batch = blockIdx&7, slice = blockIdx>>3), 256 threads, 1 neuron/thread.
// Exchange word: [tag=t+1 (hi16) | fp16 act (lo16)] — data IS the flag.
// Reload-as-poll: re-issue the full coherent 32KB reload until every embedded
// tag matches t+1 (detection == data arrival). All exchange ops sc0 sc1.
// WAR safety: writer publishes tag t+3 into pw only after its verified t+2
// reload of pw^1; peer stores t+2 only after its verified t+1 reload of pw.
// R10: gather uses bank-scheduled neighbor order (ad_stored / permuted wconn).
__global__ __launch_bounds__(256, 1) void scan_kernel(
    const float* __restrict__ cc, const int* __restrict__ ad_stored,
    const float* __restrict__ V0, const float* __restrict__ act0,
    const float* __restrict__ wconn, const float* __restrict__ decayB,
    const float* __restrict__ thrB,
    float* __restrict__ out, uint32_t* actbuf)
{
  const int tid = threadIdx.x;
  const int b   = blockIdx.x & 7;
  const int sl  = blockIdx.x >> 3;
  const int n    = sl * SLN + tid;
  const int gidx = b * NN + n;

  __shared__ float alds[NN];        // 32 KB: full act of batch b (fp32)

  // persistent per-thread state: 64 permuted weights + 64 scheduled byte offsets
  f32x4 w4[16];
  int   ad[KK];
  {
    const f32x4* wr = reinterpret_cast<const f32x4*>(wconn + (size_t)gidx * KK);
    #pragma unroll
    for (int j = 0; j < 16; ++j) w4[j] = wr[j];
    const int4* ir = reinterpret_cast<const int4*>(ad_stored + (size_t)n * KK);
    #pragma unroll
    for (int j = 0; j < KK / 4; ++j) {
      int4 v = ir[j];
      ad[4*j+0] = v.x; ad[4*j+1] = v.y;
      ad[4*j+2] = v.z; ad[4*j+3] = v.w;
    }
  }
  float V     = V0[gidx];
  float dec   = decayB[gidx];
  float onemd = 1.f - dec;
  float thr   = thrB[gidx];

  // initial act into LDS (exact fp32)
  {
    const float4* src = reinterpret_cast<const float4*>(act0 + (size_t)b * NN);
    float4* dst = reinterpret_cast<float4*>(alds);
    #pragma unroll
    for (int j = 0; j < 8; ++j) dst[tid + j * 256] = src[tid + j * 256];
  }
  __syncthreads();

  float inj = cc[((size_t)b * TT) * DD + (n >> 2)];
  const char* abase = reinterpret_cast<const char*>(alds);

  for (int t = 0; t < TT; ++t) {
    // gather + dot over 64 bank-scheduled neighbors (LDS reads: act only)
    float s0 = 0.f, s1 = 0.f, s2 = 0.f, s3 = 0.f;
    #pragma unroll
    for (int j = 0; j < 16; ++j) {
      s0 = fmaf(*reinterpret_cast<const float*>(abase + ad[4*j+0]), w4[j].x, s0);
      s1 = fmaf(*reinterpret_cast<const float*>(abase + ad[4*j+1]), w4[j].y, s1);
      s2 = fmaf(*reinterpret_cast<const float*>(abase + ad[4*j+2]), w4[j].z, s2);
      s3 = fmaf(*reinterpret_cast<const float*>(abase + ad[4*j+3]), w4[j].w, s3);
    }
    float recv = (s0 + s1) + (s2 + s3) + inj;
    V = dec * V + onemd * recv;
    float x = V - thr;
    float a = 1.f / (1.f + expf(-x));

    const int pw = t & 1;

    if (t != TT - 1) {
      // publish [tag | fp16(a)] — data and flag in one dword, device-coherent
      uint32_t word = ((uint32_t)(t + 1) << 16) |
                      (uint32_t)__half_as_ushort(__float2half_rn(a));
      uint32_t* dst = actbuf + (size_t)pw * (BS * NN) + gidx;
      asm volatile("global_store_dword %0, %1, off sc0 sc1"
                   :: "v"(dst), "v"(word) : "memory");
    }

    // group-of-4 mean (fp32 path for output)
    float p = a + __shfl_xor(a, 1);
    p = p + __shfl_xor(p, 2);
    if ((tid & 3) == 0)
      out[((size_t)b * TT + t) * DD + sl * 64 + (tid >> 2)] = 0.25f * p;

    if (t == TT - 1) break;

    // hidden under the reload-poll: next injection prefetch
    inj = cc[((size_t)b * TT + t + 1) * DD + (n >> 2)];

    // reload-as-poll: re-issue the coherent batch reload until all tags fresh
    const uint32_t* src = actbuf + (size_t)pw * (BS * NN) + (size_t)b * NN;
    const uint32_t expect = (uint32_t)(t + 1) << 16;
    u32x4 vals[8];
    for (;;) {
      #pragma unroll
      for (int j = 0; j < 8; ++j) {
        const uint32_t* p4 = src + (tid << 2) + (j << 10);
        asm volatile("global_load_dwordx4 %0, %1, off sc0 sc1"
                     : "=v"(vals[j]) : "v"(p4));
      }
      asm volatile("s_waitcnt vmcnt(0)" ::: "memory");
      uint32_t bad = 0;
      #pragma unroll
      for (int j = 0; j < 8; ++j) {
        bad |= (vals[j].x & 0xFFFF0000u) ^ expect;
        bad |= (vals[j].y & 0xFFFF0000u) ^ expect;
        bad |= (vals[j].z & 0xFFFF0000u) ^ expect;
        bad |= (vals[j].w & 0xFFFF0000u) ^ expect;
      }
      if (bad == 0) break;
    }
    // unpack fp16 payloads into LDS as fp32
    {
      const int base = (tid << 2);
      #pragma unroll
      for (int j = 0; j < 8; ++j) {
        int o = base + (j << 10);
        alds[o + 0] = __half2float(__ushort_as_half((unsigned short)(vals[j].x & 0xFFFFu)));
        alds[o + 1] = __half2float(__ushort_as_half((unsigned short)(vals[j].y & 0xFFFFu)));
        alds[o + 2] = __half2float(__ushort_as_half((unsigned short)(vals[j].z & 0xFFFFu)));
        alds[o + 3] = __half2float(__ushort_as_half((unsigned short)(vals[j].w & 0xFFFFu)));
      }
    }
    __syncthreads();
  }
}

extern "C" void kernel_launch(void* const* d_in, const int* in_sizes, int n_in,
                              void* d_out, int out_size, void* d_ws, size_t ws_size,
                              hipStream_t stream)
{
  const float* cc   = (const float*)d_in[0];
  const float* w1   = (const float*)d_in[1];
  const float* b1   = (const float*)d_in[2];
  const float* w2   = (const float*)d_in[3];
  const float* b2   = (const float*)d_in[4];
  const int*   conn = (const int*)d_in[5];
  const float* nid  = (const float*)d_in[6];
  const float* V0   = (const float*)d_in[7];
  const float* act0 = (const float*)d_in[8];
  const float* heb0 = (const float*)d_in[9];
  const float* dec0 = (const float*)d_in[10];
  const float* thr0 = (const float*)d_in[11];
  float* out = (float*)d_out;

  char* ws = (char*)d_ws;
  float*         wconn  = (float*)ws;                                   // 16 MB
  float*         decayB = (float*)(ws + (size_t)BS * NN * KK * 4);      // 256 KB
  float*         thrB   = decayB + BS * NN;                             // 256 KB
  uint32_t*      actbuf = (uint32_t*)(thrB + BS * NN);                  // 512 KB
  int*           ad_st  = (int*)(actbuf + 2 * BS * NN);                 // 2 MB
  unsigned char* inv2   = (unsigned char*)(ad_st + (size_t)NN * KK);    // 512 KB

  // zero tags every launch (replay-deterministic; first poll expects tag 1)
  hipMemsetAsync(actbuf, 0, 2 * BS * NN * sizeof(uint32_t), stream);

  prep_kernel<<<dim3(NN * KK / 256), 256, 0, stream>>>(conn, ad_st, inv2);
  modulator_kernel<<<dim3(GG), 256, 0, stream>>>(w1, b1, w2, b2, act0, heb0, dec0,
                                                 thr0, nid, inv2, wconn, decayB, thrB);
  scan_kernel<<<dim3(BS * NSL), 256, 0, stream>>>(cc, ad_st, V0, act0, wconn,
                                                  decayB, thrB, out, actbuf);
}

// Round 11
// 875.739 us; speedup vs baseline: 1.2686x; 1.0689x over previous
//
#include <hip/hip_runtime.h>
#include <hip/hip_fp16.h>
#include <cstdint>
#include <cstddef>

#define BS 8
#define TT 256
#define DD 2048
#define NN 8192
#define KK 64
#define GG 512
#define GSZ 16
#define HH 64
#define MIN_ 69
#define MOUT_ 66
#define NSL 32     // slices per batch
#define SLN 256    // neurons per slice

typedef float    f32x4 __attribute__((ext_vector_type(4)));
typedef uint32_t u32x4 __attribute__((ext_vector_type(4)));

// ---------------- Phase 0: connectivity bank-scheduling (runs once) ----------
// One wave per neuron (lane = orig position k). Stable-sort the 64 neighbor
// indices by LDS bank (key = bank*64+lane, unique). Sorted position -> bank
// has slope 1/2 (64 entries / 32 banks). Rotation stride TWO (R10 post-mortem:
// stride 1 compressed each 32-lane phase into a 16-bank window, +33%
// conflicts): r = 2*(lane&31) + (lane>>5). In round j a 32-lane phase reads
// sorted positions {j + 2l} (spacing 2) -> banks (j/2 + l) mod 32 = all 32
// banks once per phase (+- inverse-CDF noise ~2). Writes:
//   ad_stored[n][j] = neighbor byte-offset for round j
//   inv2[n][k]      = round position of orig neighbor k (weight permutation)
__global__ __launch_bounds__(256) void prep_kernel(
    const int* __restrict__ conn, int* __restrict__ ad_stored,
    unsigned char* __restrict__ inv2)
{
  const int gtid = blockIdx.x * 256 + threadIdx.x;
  const int n    = gtid >> 6;
  const int lane = gtid & 63;
  int idx  = conn[(size_t)n * KK + lane];
  int bank = idx & 31;
  unsigned key = ((unsigned)bank << 6) | (unsigned)lane;
  int rank = 0;
  #pragma unroll
  for (int i = 0; i < 64; ++i) {
    unsigned ki = (unsigned)__shfl((int)key, i);
    rank += (ki < key) ? 1 : 0;
  }
  const int ln = n & 63;                      // hardware lane of neuron n in scan
  const int r  = ((ln & 31) * 2 + (ln >> 5)) & 63;   // stride-2 de-phasing
  int j = (rank - r) & 63;
  ad_stored[(size_t)n * KK + j] = idx << 2;   // pre-scaled byte offset
  inv2[(size_t)n * KK + lane]   = (unsigned char)j;
}

// ---------------- Phase A: modulator (runs once) ----------------
// One WG per group; weights staged in LDS once, batches looped. o<KK outputs
// written PRE-PERMUTED via inv2 so scan's straight vector load of wconn pairs
// element j with ad_stored[n][j].
__global__ __launch_bounds__(256) void modulator_kernel(
    const float* __restrict__ w1, const float* __restrict__ b1,
    const float* __restrict__ w2, const float* __restrict__ b2,
    const float* __restrict__ act0, const float* __restrict__ heb0,
    const float* __restrict__ dec0, const float* __restrict__ thr0,
    const float* __restrict__ nid, const unsigned char* __restrict__ inv2,
    float* __restrict__ wconn, float* __restrict__ decayB, float* __restrict__ thrB)
{
  const int g = blockIdx.x, tid = threadIdx.x;
  __shared__ float w1s[MIN_ * HH];
  __shared__ float w2s[HH * MOUT_];
  __shared__ float b2s[MOUT_];
  __shared__ float xs[GSZ][MIN_];
  __shared__ float hd[GSZ * HH];

  for (int j = tid; j < MIN_ * HH; j += 256) w1s[j] = w1[(size_t)g * MIN_ * HH + j];
  for (int j = tid; j < HH * MOUT_; j += 256) w2s[j] = w2[(size_t)g * HH * MOUT_ + j];
  if (tid < MOUT_) b2s[tid] = b2[g * MOUT_ + tid];
  const float b1v = b1[g * HH + (tid & 63)];
  const int nbase = g * GSZ;

  for (int b = 0; b < BS; ++b) {
    __syncthreads();
    for (int j = tid; j < GSZ * KK; j += 256) {
      int s = j >> 6, k = j & 63;
      xs[s][1 + k] = heb0[((size_t)(b * NN + nbase + s)) * KK + k];
    }
    if (tid < GSZ) {
      int n = nbase + tid;
      xs[tid][0]  = act0[b * NN + n];
      xs[tid][65] = dec0[b * NN + n];
      xs[tid][66] = thr0[b * NN + n];
      xs[tid][67] = nid[2 * n];
      xs[tid][68] = nid[2 * n + 1];
    }
    __syncthreads();

    #pragma unroll
    for (int rep = 0; rep < 4; ++rep) {
      int s = rep * 4 + (tid >> 6), h = tid & 63;
      float acc = b1v;
      for (int i = 0; i < MIN_; ++i) acc = fmaf(xs[s][i], w1s[i * HH + h], acc);
      hd[s * HH + h] = tanhf(acc);
    }
    __syncthreads();

    for (int j = tid; j < GSZ * MOUT_; j += 256) {
      int s = j / MOUT_, o = j - s * MOUT_;
      float acc = b2s[o];
      for (int h = 0; h < HH; ++h) acc = fmaf(hd[s * HH + h], w2s[h * MOUT_ + o], acc);
      int nn = nbase + s;
      int gidx = b * NN + nn;
      if (o < KK) {
        int jp = inv2[(size_t)nn * KK + o];
        wconn[(size_t)gidx * KK + jp] = acc;
      }
      else if (o == KK) decayB[gidx] = 1.f / (1.f + expf(-acc));
      else              thrB[gidx]   = acc;
    }
  }
}

// ---------------- Phase B: 256-step recurrent scan (R7 protocol) ----------
// 256 WGs (batch = blockIdx&7, slice = blockIdx>>3), 256 threads, 1 neuron/thread.
// Exchange word: [tag=t+1 (hi16) | fp16 act (lo16)] — data IS the flag.
// Reload-as-poll: re-issue the full coherent 32KB reload until every embedded
// tag matches t+1 (detection == data arrival). All exchange ops sc0 sc1.
// WAR safety: writer publishes tag t+3 into pw only after its verified t+2
// reload of pw^1; peer stores t+2 only after its verified t+1 reload of pw.
// Gather uses bank-scheduled neighbor order (ad_stored / permuted wconn).
__global__ __launch_bounds__(256, 1) void scan_kernel(
    const float* __restrict__ cc, const int* __restrict__ ad_stored,
    const float* __restrict__ V0, const float* __restrict__ act0,
    const float* __restrict__ wconn, const float* __restrict__ decayB,
    const float* __restrict__ thrB,
    float* __restrict__ out, uint32_t* actbuf)
{
  const int tid = threadIdx.x;
  const int b   = blockIdx.x & 7;
  const int sl  = blockIdx.x >> 3;
  const int n    = sl * SLN + tid;
  const int gidx = b * NN + n;

  __shared__ float alds[NN];        // 32 KB: full act of batch b (fp32)

  // persistent per-thread state: 64 permuted weights + 64 scheduled byte offsets
  f32x4 w4[16];
  int   ad[KK];
  {
    const f32x4* wr = reinterpret_cast<const f32x4*>(wconn + (size_t)gidx * KK);
    #pragma unroll
    for (int j = 0; j < 16; ++j) w4[j] = wr[j];
    const int4* ir = reinterpret_cast<const int4*>(ad_stored + (size_t)n * KK);
    #pragma unroll
    for (int j = 0; j < KK / 4; ++j) {
      int4 v = ir[j];
      ad[4*j+0] = v.x; ad[4*j+1] = v.y;
      ad[4*j+2] = v.z; ad[4*j+3] = v.w;
    }
  }
  float V     = V0[gidx];
  float dec   = decayB[gidx];
  float onemd = 1.f - dec;
  float thr   = thrB[gidx];

  // initial act into LDS (exact fp32)
  {
    const float4* src = reinterpret_cast<const float4*>(act0 + (size_t)b * NN);
    float4* dst = reinterpret_cast<float4*>(alds);
    #pragma unroll
    for (int j = 0; j < 8; ++j) dst[tid + j * 256] = src[tid + j * 256];
  }
  __syncthreads();

  float inj = cc[((size_t)b * TT) * DD + (n >> 2)];
  const char* abase = reinterpret_cast<const char*>(alds);

  for (int t = 0; t < TT; ++t) {
    // gather + dot over 64 bank-scheduled neighbors (LDS reads: act only)
    float s0 = 0.f, s1 = 0.f, s2 = 0.f, s3 = 0.f;
    #pragma unroll
    for (int j = 0; j < 16; ++j) {
      s0 = fmaf(*reinterpret_cast<const float*>(abase + ad[4*j+0]), w4[j].x, s0);
      s1 = fmaf(*reinterpret_cast<const float*>(abase + ad[4*j+1]), w4[j].y, s1);
      s2 = fmaf(*reinterpret_cast<const float*>(abase + ad[4*j+2]), w4[j].z, s2);
      s3 = fmaf(*reinterpret_cast<const float*>(abase + ad[4*j+3]), w4[j].w, s3);
    }
    float recv = (s0 + s1) + (s2 + s3) + inj;
    V = dec * V + onemd * recv;
    float x = V - thr;
    float a = 1.f / (1.f + expf(-x));

    const int pw = t & 1;

    if (t != TT - 1) {
      // publish [tag | fp16(a)] — data and flag in one dword, device-coherent
      uint32_t word = ((uint32_t)(t + 1) << 16) |
                      (uint32_t)__half_as_ushort(__float2half_rn(a));
      uint32_t* dst = actbuf + (size_t)pw * (BS * NN) + gidx;
      asm volatile("global_store_dword %0, %1, off sc0 sc1"
                   :: "v"(dst), "v"(word) : "memory");
    }

    // group-of-4 mean (fp32 path for output)
    float p = a + __shfl_xor(a, 1);
    p = p + __shfl_xor(p, 2);
    if ((tid & 3) == 0)
      out[((size_t)b * TT + t) * DD + sl * 64 + (tid >> 2)] = 0.25f * p;

    if (t == TT - 1) break;

    // hidden under the reload-poll: next injection prefetch
    inj = cc[((size_t)b * TT + t + 1) * DD + (n >> 2)];

    // reload-as-poll: re-issue the coherent batch reload until all tags fresh
    const uint32_t* src = actbuf + (size_t)pw * (BS * NN) + (size_t)b * NN;
    const uint32_t expect = (uint32_t)(t + 1) << 16;
    u32x4 vals[8];
    for (;;) {
      #pragma unroll
      for (int j = 0; j < 8; ++j) {
        const uint32_t* p4 = src + (tid << 2) + (j << 10);
        asm volatile("global_load_dwordx4 %0, %1, off sc0 sc1"
                     : "=v"(vals[j]) : "v"(p4));
      }
      asm volatile("s_waitcnt vmcnt(0)" ::: "memory");
      uint32_t bad = 0;
      #pragma unroll
      for (int j = 0; j < 8; ++j) {
        bad |= (vals[j].x & 0xFFFF0000u) ^ expect;
        bad |= (vals[j].y & 0xFFFF0000u) ^ expect;
        bad |= (vals[j].z & 0xFFFF0000u) ^ expect;
        bad |= (vals[j].w & 0xFFFF0000u) ^ expect;
      }
      if (bad == 0) break;
    }
    // unpack fp16 payloads into LDS as fp32
    {
      const int base = (tid << 2);
      #pragma unroll
      for (int j = 0; j < 8; ++j) {
        int o = base + (j << 10);
        alds[o + 0] = __half2float(__ushort_as_half((unsigned short)(vals[j].x & 0xFFFFu)));
        alds[o + 1] = __half2float(__ushort_as_half((unsigned short)(vals[j].y & 0xFFFFu)));
        alds[o + 2] = __half2float(__ushort_as_half((unsigned short)(vals[j].z & 0xFFFFu)));
        alds[o + 3] = __half2float(__ushort_as_half((unsigned short)(vals[j].w & 0xFFFFu)));
      }
    }
    __syncthreads();
  }
}

extern "C" void kernel_launch(void* const* d_in, const int* in_sizes, int n_in,
                              void* d_out, int out_size, void* d_ws, size_t ws_size,
                              hipStream_t stream)
{
  const float* cc   = (const float*)d_in[0];
  const float* w1   = (const float*)d_in[1];
  const float* b1   = (const float*)d_in[2];
  const float* w2   = (const float*)d_in[3];
  const float* b2   = (const float*)d_in[4];
  const int*   conn = (const int*)d_in[5];
  const float* nid  = (const float*)d_in[6];
  const float* V0   = (const float*)d_in[7];
  const float* act0 = (const float*)d_in[8];
  const float* heb0 = (const float*)d_in[9];
  const float* dec0 = (const float*)d_in[10];
  const float* thr0 = (const float*)d_in[11];
  float* out = (float*)d_out;

  char* ws = (char*)d_ws;
  float*         wconn  = (float*)ws;                                   // 16 MB
  float*         decayB = (float*)(ws + (size_t)BS * NN * KK * 4);      // 256 KB
  float*         thrB   = decayB + BS * NN;                             // 256 KB
  uint32_t*      actbuf = (uint32_t*)(thrB + BS * NN);                  // 512 KB
  int*           ad_st  = (int*)(actbuf + 2 * BS * NN);                 // 2 MB
  unsigned char* inv2   = (unsigned char*)(ad_st + (size_t)NN * KK);    // 512 KB

  // zero tags every launch (replay-deterministic; first poll expects tag 1)
  hipMemsetAsync(actbuf, 0, 2 * BS * NN * sizeof(uint32_t), stream);

  prep_kernel<<<dim3(NN * KK / 256), 256, 0, stream>>>(conn, ad_st, inv2);
  modulator_kernel<<<dim3(GG), 256, 0, stream>>>(w1, b1, w2, b2, act0, heb0, dec0,
                                                 thr0, nid, inv2, wconn, decayB, thrB);
  scan_kernel<<<dim3(BS * NSL), 256, 0, stream>>>(cc, ad_st, V0, act0, wconn,
                                                  decayB, thrB, out, actbuf);
}

// Round 12
// 775.513 us; speedup vs baseline: 1.4325x; 1.1292x over previous
//
#include <hip/hip_runtime.h>
#include <cstdint>
#include <cstddef>

#define BS 8
#define TT 256
#define DD 2048
#define NN 8192
#define KK 64
#define GG 512
#define GSZ 16
#define HH 64
#define MIN_ 69
#define MOUT_ 66
#define NSL 32     // slices per batch
#define SLN 256    // neurons per slice
#define NW (NN/2)  // packed words per batch (4096)

typedef float    f32x4 __attribute__((ext_vector_type(4)));
typedef uint32_t u32x4 __attribute__((ext_vector_type(4)));

// ---------------- Phase 0: connectivity bank-scheduling (runs once) ----------
// One wave per neuron (lane = orig position k). Stable-sort the 64 neighbor
// indices by PACKED-WORD LDS bank ((idx>>1)&31; two neurons share a dword),
// key = bank*64+lane (unique). Rotation stride 2 (R10/R11): in round j a
// 32-lane phase reads sorted positions {j+2l} -> banks ~ (j/2+l) mod 32 =
// all 32 banks once per phase. Writes:
//   ad_stored[n][j] = (word byte-offset) | (idx&1)   [bit0 = 12-bit field sel]
//   inv2[n][k]      = round position of orig neighbor k (weight permutation)
__global__ __launch_bounds__(256) void prep_kernel(
    const int* __restrict__ conn, int* __restrict__ ad_stored,
    unsigned char* __restrict__ inv2)
{
  const int gtid = blockIdx.x * 256 + threadIdx.x;
  const int n    = gtid >> 6;
  const int lane = gtid & 63;
  int idx  = conn[(size_t)n * KK + lane];
  int bank = (idx >> 1) & 31;
  unsigned key = ((unsigned)bank << 6) | (unsigned)lane;
  int rank = 0;
  #pragma unroll
  for (int i = 0; i < 64; ++i) {
    unsigned ki = (unsigned)__shfl((int)key, i);
    rank += (ki < key) ? 1 : 0;
  }
  const int ln = n & 63;                             // hw lane of neuron n in scan
  const int r  = ((ln & 31) * 2 + (ln >> 5)) & 63;   // stride-2 de-phasing
  int j = (rank - r) & 63;
  ad_stored[(size_t)n * KK + j] = ((idx >> 1) << 2) | (idx & 1);
  inv2[(size_t)n * KK + lane]   = (unsigned char)j;
}

// ---------------- Phase A: modulator (runs once) ----------------
// One WG per group; weights staged in LDS once, batches looped. o<KK outputs
// written PRE-PERMUTED via inv2 so scan's straight vector load of wconn pairs
// element j with ad_stored[n][j].
__global__ __launch_bounds__(256) void modulator_kernel(
    const float* __restrict__ w1, const float* __restrict__ b1,
    const float* __restrict__ w2, const float* __restrict__ b2,
    const float* __restrict__ act0, const float* __restrict__ heb0,
    const float* __restrict__ dec0, const float* __restrict__ thr0,
    const float* __restrict__ nid, const unsigned char* __restrict__ inv2,
    float* __restrict__ wconn, float* __restrict__ decayB, float* __restrict__ thrB)
{
  const int g = blockIdx.x, tid = threadIdx.x;
  __shared__ float w1s[MIN_ * HH];
  __shared__ float w2s[HH * MOUT_];
  __shared__ float b2s[MOUT_];
  __shared__ float xs[GSZ][MIN_];
  __shared__ float hd[GSZ * HH];

  for (int j = tid; j < MIN_ * HH; j += 256) w1s[j] = w1[(size_t)g * MIN_ * HH + j];
  for (int j = tid; j < HH * MOUT_; j += 256) w2s[j] = w2[(size_t)g * HH * MOUT_ + j];
  if (tid < MOUT_) b2s[tid] = b2[g * MOUT_ + tid];
  const float b1v = b1[g * HH + (tid & 63)];
  const int nbase = g * GSZ;

  for (int b = 0; b < BS; ++b) {
    __syncthreads();
    for (int j = tid; j < GSZ * KK; j += 256) {
      int s = j >> 6, k = j & 63;
      xs[s][1 + k] = heb0[((size_t)(b * NN + nbase + s)) * KK + k];
    }
    if (tid < GSZ) {
      int n = nbase + tid;
      xs[tid][0]  = act0[b * NN + n];
      xs[tid][65] = dec0[b * NN + n];
      xs[tid][66] = thr0[b * NN + n];
      xs[tid][67] = nid[2 * n];
      xs[tid][68] = nid[2 * n + 1];
    }
    __syncthreads();

    #pragma unroll
    for (int rep = 0; rep < 4; ++rep) {
      int s = rep * 4 + (tid >> 6), h = tid & 63;
      float acc = b1v;
      for (int i = 0; i < MIN_; ++i) acc = fmaf(xs[s][i], w1s[i * HH + h], acc);
      hd[s * HH + h] = tanhf(acc);
    }
    __syncthreads();

    for (int j = tid; j < GSZ * MOUT_; j += 256) {
      int s = j / MOUT_, o = j - s * MOUT_;
      float acc = b2s[o];
      for (int h = 0; h < HH; ++h) acc = fmaf(hd[s * HH + h], w2s[h * MOUT_ + o], acc);
      int nn = nbase + s;
      int gidx = b * NN + nn;
      if (o < KK) {
        int jp = inv2[(size_t)nn * KK + o];
        wconn[(size_t)gidx * KK + jp] = acc;
      }
      else if (o == KK) decayB[gidx] = 1.f / (1.f + expf(-acc));
      else              thrB[gidx]   = acc;
    }
  }
}

// ---------------- Phase B: 256-step recurrent scan (R7 protocol, packed) ----
// 256 WGs (batch = blockIdx&7, slice = blockIdx>>3), 256 threads, 1 neuron/thread.
// Exchange word: [tag8 | act12(odd) | act12(even)] — TWO neurons per dword,
// 12-bit fixed-point (quant err 1.2e-4 <= fp16; tags 1..255, no wrap per
// parity). Data IS the flag. Reload-as-poll: re-issue the 16KB coherent
// reload until every byte-tag matches t+1. All exchange ops sc0 sc1.
// WAR safety: identical induction to R6-R11 (writer publishes tag t+3 into
// pw only after verified t+2 reload of pw^1; peer stores t+2 only after its
// verified t+1 reload of pw).
// LDS holds the PACKED words (16KB); gather extracts the 12-bit field with a
// shift from a precomputed parity bitmask; weights pre-scaled by 1/4095.
__global__ __launch_bounds__(256, 1) void scan_kernel(
    const float* __restrict__ cc, const int* __restrict__ ad_stored,
    const float* __restrict__ V0, const float* __restrict__ act0,
    const float* __restrict__ wconn, const float* __restrict__ decayB,
    const float* __restrict__ thrB,
    float* __restrict__ out, uint32_t* actbuf)
{
  const int tid = threadIdx.x;
  const int b   = blockIdx.x & 7;
  const int sl  = blockIdx.x >> 3;
  const int n    = sl * SLN + tid;
  const int gidx = b * NN + n;

  __shared__ uint32_t alds[NW];     // 16 KB: packed acts of batch b

  // persistent per-thread state: 64 permuted pre-scaled weights,
  // 64 scheduled word byte-offsets, 64-bit field-parity mask
  f32x4 w4[16];
  int   ad[KK];
  uint32_t mlo = 0, mhi = 0;
  {
    const f32x4* wr = reinterpret_cast<const f32x4*>(wconn + (size_t)gidx * KK);
    #pragma unroll
    for (int j = 0; j < 16; ++j) {
      f32x4 v = wr[j];
      w4[j] = v * (1.f / 4095.f);
    }
    const int4* ir = reinterpret_cast<const int4*>(ad_stored + (size_t)n * KK);
    #pragma unroll
    for (int j = 0; j < KK / 4; ++j) {
      int4 v = ir[j];
      ad[4*j+0] = v.x; ad[4*j+1] = v.y;
      ad[4*j+2] = v.z; ad[4*j+3] = v.w;
    }
    #pragma unroll
    for (int k = 0; k < 32; ++k) { mlo |= (uint32_t)(ad[k] & 1) << k;      ad[k] &= ~1; }
    #pragma unroll
    for (int k = 32; k < 64; ++k) { mhi |= (uint32_t)(ad[k] & 1) << (k-32); ad[k] &= ~1; }
  }
  float V     = V0[gidx];
  float dec   = decayB[gidx];
  float onemd = 1.f - dec;
  float thr   = thrB[gidx];

  // initial act into LDS, packed to the same 12-bit format
  for (int w = tid; w < NW; w += 256) {
    float a0 = act0[(size_t)b * NN + 2 * w];
    float a1 = act0[(size_t)b * NN + 2 * w + 1];
    uint32_t q0 = (uint32_t)__builtin_rintf(a0 * 4095.f);
    uint32_t q1 = (uint32_t)__builtin_rintf(a1 * 4095.f);
    alds[w] = (q1 << 12) | q0;
  }
  __syncthreads();

  float inj = cc[((size_t)b * TT) * DD + (n >> 2)];
  const char* abase = reinterpret_cast<const char*>(alds);

  for (int t = 0; t < TT; ++t) {
    // gather + dot over 64 bank-scheduled packed neighbors
    float s0 = 0.f, s1 = 0.f, s2 = 0.f, s3 = 0.f;
    #pragma unroll
    for (int j = 0; j < 16; ++j) {
      uint32_t d0 = *reinterpret_cast<const uint32_t*>(abase + ad[4*j+0]);
      uint32_t d1 = *reinterpret_cast<const uint32_t*>(abase + ad[4*j+1]);
      uint32_t d2 = *reinterpret_cast<const uint32_t*>(abase + ad[4*j+2]);
      uint32_t d3 = *reinterpret_cast<const uint32_t*>(abase + ad[4*j+3]);
      uint32_t sh0, sh1, sh2, sh3;
      if (4*j+3 < 32) {
        sh0 = ((mlo >> (4*j+0)) & 1) * 12; sh1 = ((mlo >> (4*j+1)) & 1) * 12;
        sh2 = ((mlo >> (4*j+2)) & 1) * 12; sh3 = ((mlo >> (4*j+3)) & 1) * 12;
      } else {
        sh0 = ((mhi >> (4*j+0-32)) & 1) * 12; sh1 = ((mhi >> (4*j+1-32)) & 1) * 12;
        sh2 = ((mhi >> (4*j+2-32)) & 1) * 12; sh3 = ((mhi >> (4*j+3-32)) & 1) * 12;
      }
      s0 = fmaf((float)((d0 >> sh0) & 0xFFFu), w4[j].x, s0);
      s1 = fmaf((float)((d1 >> sh1) & 0xFFFu), w4[j].y, s1);
      s2 = fmaf((float)((d2 >> sh2) & 0xFFFu), w4[j].z, s2);
      s3 = fmaf((float)((d3 >> sh3) & 0xFFFu), w4[j].w, s3);
    }
    float recv = (s0 + s1) + (s2 + s3) + inj;
    V = dec * V + onemd * recv;
    float x = V - thr;
    float a = 1.f / (1.f + expf(-x));

    const int pw = t & 1;

    if (t != TT - 1) {
      // publish packed pair (even lanes): [tag8 | q(odd) | q(even)]
      uint32_t aq = (uint32_t)__builtin_rintf(a * 4095.f);
      uint32_t oq = (uint32_t)__shfl_xor((int)aq, 1);
      if ((tid & 1) == 0) {
        uint32_t word = ((uint32_t)(t + 1) << 24) | (oq << 12) | aq;
        uint32_t* dst = actbuf + (size_t)pw * (BS * NW) + (gidx >> 1);
        asm volatile("global_store_dword %0, %1, off sc0 sc1"
                     :: "v"(dst), "v"(word) : "memory");
      }
    }

    // group-of-4 mean (fp32 path for output)
    float p = a + __shfl_xor(a, 1);
    p = p + __shfl_xor(p, 2);
    if ((tid & 3) == 0)
      out[((size_t)b * TT + t) * DD + sl * 64 + (tid >> 2)] = 0.25f * p;

    if (t == TT - 1) break;

    // hidden under the reload-poll: next injection prefetch
    inj = cc[((size_t)b * TT + t + 1) * DD + (n >> 2)];

    // reload-as-poll: re-issue the 16KB coherent reload until all tags fresh
    const uint32_t* src = actbuf + (size_t)pw * (BS * NW) + (size_t)b * NW;
    const uint32_t tag = (uint32_t)(t + 1);
    u32x4 vals[4];
    for (;;) {
      #pragma unroll
      for (int j = 0; j < 4; ++j) {
        const uint32_t* p4 = src + (tid << 2) + (j << 10);
        asm volatile("global_load_dwordx4 %0, %1, off sc0 sc1"
                     : "=v"(vals[j]) : "v"(p4));
      }
      asm volatile("s_waitcnt vmcnt(0)" ::: "memory");
      uint32_t bad = 0;
      #pragma unroll
      for (int j = 0; j < 4; ++j) {
        bad |= (vals[j].x >> 24) ^ tag;
        bad |= (vals[j].y >> 24) ^ tag;
        bad |= (vals[j].z >> 24) ^ tag;
        bad |= (vals[j].w >> 24) ^ tag;
      }
      if (bad == 0) break;
    }
    // packed words straight into LDS (no unpack pass)
    {
      u32x4* dst = reinterpret_cast<u32x4*>(alds);
      #pragma unroll
      for (int j = 0; j < 4; ++j) dst[tid + j * 256] = vals[j];
    }
    __syncthreads();
  }
}

extern "C" void kernel_launch(void* const* d_in, const int* in_sizes, int n_in,
                              void* d_out, int out_size, void* d_ws, size_t ws_size,
                              hipStream_t stream)
{
  const float* cc   = (const float*)d_in[0];
  const float* w1   = (const float*)d_in[1];
  const float* b1   = (const float*)d_in[2];
  const float* w2   = (const float*)d_in[3];
  const float* b2   = (const float*)d_in[4];
  const int*   conn = (const int*)d_in[5];
  const float* nid  = (const float*)d_in[6];
  const float* V0   = (const float*)d_in[7];
  const float* act0 = (const float*)d_in[8];
  const float* heb0 = (const float*)d_in[9];
  const float* dec0 = (const float*)d_in[10];
  const float* thr0 = (const float*)d_in[11];
  float* out = (float*)d_out;

  char* ws = (char*)d_ws;
  float*         wconn  = (float*)ws;                                   // 16 MB
  float*         decayB = (float*)(ws + (size_t)BS * NN * KK * 4);      // 256 KB
  float*         thrB   = decayB + BS * NN;                             // 256 KB
  uint32_t*      actbuf = (uint32_t*)(thrB + BS * NN);                  // 2*8*4096 dw
  int*           ad_st  = (int*)(actbuf + 2 * BS * NW);                 // 2 MB
  unsigned char* inv2   = (unsigned char*)(ad_st + (size_t)NN * KK);    // 512 KB

  // zero tags every launch (replay-deterministic; first poll expects tag 1)
  hipMemsetAsync(actbuf, 0, 2 * BS * NW * sizeof(uint32_t), stream);

  prep_kernel<<<dim3(NN * KK / 256), 256, 0, stream>>>(conn, ad_st, inv2);
  modulator_kernel<<<dim3(GG), 256, 0, stream>>>(w1, b1, w2, b2, act0, heb0, dec0,
                                                 thr0, nid, inv2, wconn, decayB, thrB);
  scan_kernel<<<dim3(BS * NSL), 256, 0, stream>>>(cc, ad_st, V0, act0, wconn,
                                                  decayB, thrB, out, actbuf);
}